// Round 9
// baseline (55.450 us; speedup 1.0000x reference)
//
#include <hip/hip_runtime.h>
#include <hip/hip_bf16.h>

// BlockLinear: out[h*64+i][b] = sum_j W[h][i][j] * inp[h*64+j][b]
// Round 9: r7/r8 swapped-operand MFMA structure, but ALL memory ops use
// wave-uniform SGPR base + 32-bit per-lane element offsets (saddr-form
// global_load_dword). Address-VGPR pressure was the hidden MLP serializer:
// 64-bit per-load addresses (row stride 128 KB >> imm range) needed 2 VGPRs
// per load -> compiler batched loads ~8 at a time. Now: 16 x-offset regs
// (+imm folds for mi/tile), 4 W-offset regs, 4 out-offset regs.
// nt-store reverted (r8: WRITE 137->166 MB, no FETCH gain).
// Fragment layout (HW-validated r6-r8): lane l holds k = ks*32 + 8*(l>>4)+r;
// C/D: batch m = 4*(l>>4)+reg, i = l&15.

constexpr int H   = 16;
constexpr int D   = 64;
constexpr int B   = 32768;
constexpr int TPB = 128;   // cols per tile per block (4 waves x 32)
constexpr int NT  = 2;     // tiles per block

using bf16x8 = __attribute__((ext_vector_type(8))) short;
using f32x4  = __attribute__((ext_vector_type(4))) float;

__device__ inline unsigned pk2(float a, float b) {
    __hip_bfloat162 h2 = __float22bfloat162_rn(make_float2(a, b));
    union { __hip_bfloat162 h; unsigned u; } c;
    c.h = h2;
    return c.u;   // low 16 = a, high 16 = b
}

__global__ __launch_bounds__(256)
void block_linear_mfma(const float* __restrict__ W,
                       const float* __restrict__ inp,
                       float* __restrict__ out)
{
    const int tid = threadIdx.x;
    const int l   = tid & 63;
    const int wv  = __builtin_amdgcn_readfirstlane(tid >> 6);
    const int h   = blockIdx.y;
    const int l15 = l & 15;
    const int lk8 = (l >> 4) * 8;
    const int lr4 = (l >> 4) * 4;

    // Wave-uniform SGPR bases; all per-lane offsets are 32-bit element counts.
    const float* __restrict__ Wb = W   + (size_t)h * D * D;
    const float* __restrict__ Xb = inp + (size_t)h * D * B;
    float*       __restrict__ Ob = out + (size_t)h * D * B;

    const unsigned colbase = (unsigned)blockIdx.x * (TPB * NT) + wv * 32;

    // ---- Per-lane 32-bit offset registers.
    unsigned woff[4];                  // W: rows 16*ni + l15, col base lk8
    #pragma unroll
    for (int ni = 0; ni < 4; ++ni)
        woff[ni] = (unsigned)(16 * ni + l15) * D + lk8;

    unsigned xoff[2][8];               // X: row (ks*32+lk8+r), col colbase+l15
    #pragma unroll
    for (int ks = 0; ks < 2; ++ks)
        #pragma unroll
        for (int r = 0; r < 8; ++r)
            xoff[ks][r] = (unsigned)(ks * 32 + lk8 + r) * B + colbase + l15;

    unsigned ooff[4];                  // out: row (16*ni+l15), col colbase+lr4
    #pragma unroll
    for (int ni = 0; ni < 4; ++ni)
        ooff[ni] = (unsigned)(16 * ni + l15) * B + colbase + lr4;

    // ---- 1) W raw loads (16 float4; imm offset covers ks*32 and +4).
    float4 wq[4][2][2];
    #pragma unroll
    for (int ni = 0; ni < 4; ++ni)
        #pragma unroll
        for (int ks = 0; ks < 2; ++ks) {
            wq[ni][ks][0] = *(const float4*)(Wb + woff[ni] + ks * 32);
            wq[ni][ks][1] = *(const float4*)(Wb + woff[ni] + ks * 32 + 4);
        }

    // ---- 2) Tile-0 x loads (32 dwords; imm offset covers +16*mi).
    float xA[2][2][8];
    #pragma unroll
    for (int mi = 0; mi < 2; ++mi)
        #pragma unroll
        for (int ks = 0; ks < 2; ++ks)
            #pragma unroll
            for (int r = 0; r < 8; ++r)
                xA[mi][ks][r] = Xb[xoff[ks][r] + 16 * mi];

    // ---- 3) Convert W while x stays in flight (counted vmcnt).
    bf16x8 bfrag[4][2];
    #pragma unroll
    for (int ni = 0; ni < 4; ++ni)
        #pragma unroll
        for (int ks = 0; ks < 2; ++ks) {
            union { bf16x8 v; unsigned u[4]; } f;
            f.u[0] = pk2(wq[ni][ks][0].x, wq[ni][ks][0].y);
            f.u[1] = pk2(wq[ni][ks][0].z, wq[ni][ks][0].w);
            f.u[2] = pk2(wq[ni][ks][1].x, wq[ni][ks][1].y);
            f.u[3] = pk2(wq[ni][ks][1].z, wq[ni][ks][1].w);
            bfrag[ni][ks] = f.v;
        }

    // ---- 4) Tile-1 x loads (imm offset covers +TPB = 512 B).
    float xB[2][2][8];
    #pragma unroll
    for (int mi = 0; mi < 2; ++mi)
        #pragma unroll
        for (int ks = 0; ks < 2; ++ks)
            #pragma unroll
            for (int r = 0; r < 8; ++r)
                xB[mi][ks][r] = Xb[xoff[ks][r] + 16 * mi + TPB];

    // ---- 5) Process tiles: convert -> 16 MFMA -> 8 float4 stores.
#define PROCESS_TILE(XBUF, T)                                                  \
    do {                                                                       \
        bf16x8 a[2][2];                                                        \
        _Pragma("unroll")                                                      \
        for (int mi = 0; mi < 2; ++mi)                                         \
            _Pragma("unroll")                                                  \
            for (int ks = 0; ks < 2; ++ks) {                                   \
                const float* e = XBUF[mi][ks];                                 \
                union { bf16x8 v; unsigned u[4]; } f;                          \
                f.u[0] = pk2(e[0], e[1]);                                      \
                f.u[1] = pk2(e[2], e[3]);                                      \
                f.u[2] = pk2(e[4], e[5]);                                      \
                f.u[3] = pk2(e[6], e[7]);                                      \
                a[mi][ks] = f.v;                                               \
            }                                                                  \
        _Pragma("unroll")                                                      \
        for (int mi = 0; mi < 2; ++mi)                                         \
            _Pragma("unroll")                                                  \
            for (int ni = 0; ni < 4; ++ni) {                                   \
                f32x4 c = {0.f, 0.f, 0.f, 0.f};                                \
                c = __builtin_amdgcn_mfma_f32_16x16x32_bf16(a[mi][0],          \
                        bfrag[ni][0], c, 0, 0, 0);                             \
                c = __builtin_amdgcn_mfma_f32_16x16x32_bf16(a[mi][1],          \
                        bfrag[ni][1], c, 0, 0, 0);                             \
                float* op = Ob + ooff[ni] + (T) * TPB + 16 * mi;               \
                float4 v = make_float4(c[0], c[1], c[2], c[3]);                \
                *(float4*)op = v;                                              \
            }                                                                  \
    } while (0)

    PROCESS_TILE(xA, 0);
    PROCESS_TILE(xB, 1);
#undef PROCESS_TILE
}

extern "C" void kernel_launch(void* const* d_in, const int* in_sizes, int n_in,
                              void* d_out, int out_size, void* d_ws, size_t ws_size,
                              hipStream_t stream) {
    const float* W   = (const float*)d_in[0];
    const float* inp = (const float*)d_in[1];
    float*       out = (float*)d_out;

    dim3 grid(B / (TPB * NT), H);   // 128 x 16 = 2048 workgroups
    block_linear_mfma<<<grid, dim3(256), 0, stream>>>(W, inp, out);
}